// Round 1
// baseline (228.782 us; speedup 1.0000x reference)
//
#include <hip/hip_runtime.h>
#include <stdint.h>

#define S_ 2048
#define SS_ (S_ * S_)

typedef __bf16 bf16x8 __attribute__((ext_vector_type(8)));
typedef float f32x4 __attribute__((ext_vector_type(4)));
typedef unsigned int u32x4 __attribute__((ext_vector_type(4)));

union FragU {
    u32x4 u;
    bf16x8 v;
    unsigned short s[8];
};

__device__ __forceinline__ unsigned short f2bf(float f) {
    unsigned int u = __builtin_bit_cast(unsigned int, f);
    u += 0x7fffu + ((u >> 16) & 1u);   // round-to-nearest-even
    return (unsigned short)(u >> 16);
}

// ---------- Stage 0: weights fp32 -> bf16 (3 x 64x1024) ----------
__global__ __launch_bounds__(256) void cvt_w_kernel(
    const float* __restrict__ wq, const float* __restrict__ wk,
    const float* __restrict__ wv, unsigned short* __restrict__ out)
{
    int i = blockIdx.x * 256 + threadIdx.x;   // one thread per 4 elements
    int mat = i >> 14;                        // 16384 float4 per 65536-elem matrix
    int off = (i & 16383) << 2;
    const float* src = (mat == 0) ? wq : (mat == 1) ? wk : wv;
    float4 v = *(const float4*)(src + off);
    ushort4 o;
    o.x = f2bf(v.x); o.y = f2bf(v.y); o.z = f2bf(v.z); o.w = f2bf(v.w);
    *(ushort4*)(out + mat * 65536 + off) = o;
}

// ---------- Stage 1: projections via MFMA 16x16x32 bf16 ----------
// C[row][d] = sum_u X[row][u] * W[d][u] + bias[d]
// One wave per 16 rows. grid = (8192/16, 3)
__global__ __launch_bounds__(64) void proj_kernel(
    const float* __restrict__ Q, const float* __restrict__ K, const float* __restrict__ V,
    const unsigned short* __restrict__ Wb,      // [3][64][1024] bf16
    const float* __restrict__ Bq, const float* __restrict__ Bk, const float* __restrict__ Bv,
    unsigned short* __restrict__ Qb, unsigned short* __restrict__ Kb,
    unsigned short* __restrict__ Vt)            // Vt: [B][64][S]
{
    const int lane = threadIdx.x;
    const int lm = lane & 15, quad = lane >> 4;
    const int mat = blockIdx.y;
    const int row0 = blockIdx.x * 16;

    const float* X    = (mat == 0) ? Q  : (mat == 1) ? K  : V;
    const float* Bias = (mat == 0) ? Bq : (mat == 1) ? Bk : Bv;
    const unsigned short* W = Wb + mat * (64 * 1024);

    f32x4 acc[4];
    #pragma unroll
    for (int ct = 0; ct < 4; ++ct) { f32x4 z = {0.f,0.f,0.f,0.f}; acc[ct] = z; }

    const float* aptr = X + (row0 + lm) * 1024 + quad * 8;

    for (int k0 = 0; k0 < 1024; k0 += 32) {
        FragU af;
        float4 a0 = *(const float4*)(aptr + k0);
        float4 a1 = *(const float4*)(aptr + k0 + 4);
        af.s[0] = f2bf(a0.x); af.s[1] = f2bf(a0.y); af.s[2] = f2bf(a0.z); af.s[3] = f2bf(a0.w);
        af.s[4] = f2bf(a1.x); af.s[5] = f2bf(a1.y); af.s[6] = f2bf(a1.z); af.s[7] = f2bf(a1.w);
        #pragma unroll
        for (int ct = 0; ct < 4; ++ct) {
            FragU bfr;
            bfr.u = *(const u32x4*)(W + (ct * 16 + lm) * 1024 + k0 + quad * 8);
            acc[ct] = __builtin_amdgcn_mfma_f32_16x16x32_bf16(af.v, bfr.v, acc[ct], 0, 0, 0);
        }
    }

    #pragma unroll
    for (int ct = 0; ct < 4; ++ct) {
        int col = ct * 16 + lm;
        float bv = Bias[col];
        #pragma unroll
        for (int r = 0; r < 4; ++r) {
            int row = row0 + quad * 4 + r;   // global row = b*2048 + s
            unsigned short h = f2bf(acc[ct][r] + bv);
            if (mat == 0)      Qb[row * 64 + col] = h;
            else if (mat == 1) Kb[row * 64 + col] = h;
            else               Vt[(row >> 11) * (64 * 2048) + col * 2048 + (row & 2047)] = h;
        }
    }
}

// ---------- Stage 2: masked flash attention ----------
// block = 256 thr = 4 waves; each block = one 16-query tile of one batch.
// wave w handles keys [w*512, (w+1)*512); partials merged in LDS.
__global__ __launch_bounds__(256) void attn_kernel(
    const unsigned short* __restrict__ Qb, const unsigned short* __restrict__ Kb,
    const unsigned short* __restrict__ Vt, const int* __restrict__ mask,
    float* __restrict__ out)
{
    const int tid = threadIdx.x;
    const int w = tid >> 6;
    const int lane = tid & 63;
    const int lm = lane & 15, quad = lane >> 4;
    const int b = blockIdx.y;
    const int q0 = blockIdx.x * 16;

    __shared__ unsigned short Plds[4][16 * 80];   // stride 80 keeps b128 reads aligned
    __shared__ float Olds[4][16 * 64];
    __shared__ float mlds[4][16];
    __shared__ float llds[4][16];

    // Q fragments (A-layout): held for whole kernel
    FragU qf0, qf1;
    const unsigned short* qptr = Qb + (b * 2048 + q0 + lm) * 64 + quad * 8;
    qf0.u = *(const u32x4*)(qptr);
    qf1.u = *(const u32x4*)(qptr + 32);

    f32x4 o[4];
    #pragma unroll
    for (int dt = 0; dt < 4; ++dt) { f32x4 z = {0.f,0.f,0.f,0.f}; o[dt] = z; }
    float mrun[4] = {-3e38f, -3e38f, -3e38f, -3e38f};
    float lrun[4] = {0.f, 0.f, 0.f, 0.f};

    const int* mbase = mask + b * SS_;
    int rowoff[4];
    #pragma unroll
    for (int r = 0; r < 4; ++r) rowoff[r] = (q0 + quad * 4 + r) * S_;

    for (int iter = 0; iter < 8; ++iter) {
        const int k0 = w * 512 + iter * 64;

        // ---- scores: 16q x 64k ----
        f32x4 sc[4];
        #pragma unroll
        for (int ct = 0; ct < 4; ++ct) {
            f32x4 a = {0.f,0.f,0.f,0.f};
            const unsigned short* kptr = Kb + (b * 2048 + k0 + ct * 16 + lm) * 64 + quad * 8;
            FragU kf0, kf1;
            kf0.u = *(const u32x4*)(kptr);
            kf1.u = *(const u32x4*)(kptr + 32);
            a = __builtin_amdgcn_mfma_f32_16x16x32_bf16(qf0.v, kf0.v, a, 0, 0, 0);
            a = __builtin_amdgcn_mfma_f32_16x16x32_bf16(qf1.v, kf1.v, a, 0, 0, 0);
            sc[ct] = a;
        }

        // ---- scale + mask (masked = s*m - 1e9*(1-m), m in {0,1}) ----
        #pragma unroll
        for (int ct = 0; ct < 4; ++ct) {
            #pragma unroll
            for (int r = 0; r < 4; ++r) {
                int key = k0 + ct * 16 + lm;
                int mv = mbase[rowoff[r] + key];
                float s = sc[ct][r] * 0.125f;
                sc[ct][r] = mv ? s : -1.0e9f;
            }
        }

        // ---- online softmax per q-row (rows live in 16-lane quads) ----
        float alpha[4];
        #pragma unroll
        for (int r = 0; r < 4; ++r) {
            float vmx = fmaxf(fmaxf(sc[0][r], sc[1][r]), fmaxf(sc[2][r], sc[3][r]));
            #pragma unroll
            for (int off = 1; off <= 8; off <<= 1)
                vmx = fmaxf(vmx, __shfl_xor(vmx, off, 64));
            float mnew = fmaxf(mrun[r], vmx);
            alpha[r] = __expf(mrun[r] - mnew);
            mrun[r] = mnew;
            float rs = 0.f;
            #pragma unroll
            for (int ct = 0; ct < 4; ++ct) {
                float pv = __expf(sc[ct][r] - mnew);
                sc[ct][r] = pv;
                rs += pv;
            }
            #pragma unroll
            for (int off = 1; off <= 8; off <<= 1)
                rs += __shfl_xor(rs, off, 64);
            lrun[r] = lrun[r] * alpha[r] + rs;
        }

        // rescale O
        #pragma unroll
        for (int dt = 0; dt < 4; ++dt)
            #pragma unroll
            for (int r = 0; r < 4; ++r)
                o[dt][r] *= alpha[r];

        // ---- P: C-layout -> A-layout via LDS ----
        #pragma unroll
        for (int ct = 0; ct < 4; ++ct)
            #pragma unroll
            for (int r = 0; r < 4; ++r)
                Plds[w][(quad * 4 + r) * 80 + ct * 16 + lm] = f2bf(sc[ct][r]);
        __syncthreads();

        // ---- PV: O += P[16x64] * V[64keys x 64dims] ----
        #pragma unroll
        for (int ks = 0; ks < 2; ++ks) {
            FragU pf;
            pf.u = *(const u32x4*)&Plds[w][lm * 80 + ks * 32 + quad * 8];
            #pragma unroll
            for (int dt = 0; dt < 4; ++dt) {
                FragU vf;
                vf.u = *(const u32x4*)(Vt + b * (64 * 2048) + (dt * 16 + lm) * 2048
                                       + k0 + ks * 32 + quad * 8);
                o[dt] = __builtin_amdgcn_mfma_f32_16x16x32_bf16(pf.v, vf.v, o[dt], 0, 0, 0);
            }
        }
        __syncthreads();
    }

    // ---- write per-wave partials ----
    #pragma unroll
    for (int dt = 0; dt < 4; ++dt)
        #pragma unroll
        for (int r = 0; r < 4; ++r)
            Olds[w][(quad * 4 + r) * 64 + dt * 16 + lm] = o[dt][r];
    if (lm == 0) {
        #pragma unroll
        for (int r = 0; r < 4; ++r) {
            mlds[w][quad * 4 + r] = mrun[r];
            llds[w][quad * 4 + r] = lrun[r];
        }
    }
    __syncthreads();

    // ---- merge 4 wave-partials, normalize, store fp32 ----
    #pragma unroll
    for (int i = 0; i < 4; ++i) {
        int e = i * 256 + tid;        // 1024 outputs per block
        int q = e >> 6, d = e & 63;
        float m0 = mlds[0][q], m1 = mlds[1][q], m2 = mlds[2][q], m3 = mlds[3][q];
        float M = fmaxf(fmaxf(m0, m1), fmaxf(m2, m3));
        float e0 = __expf(m0 - M), e1 = __expf(m1 - M), e2 = __expf(m2 - M), e3 = __expf(m3 - M);
        float L = llds[0][q] * e0 + llds[1][q] * e1 + llds[2][q] * e2 + llds[3][q] * e3;
        float val = Olds[0][q * 64 + d] * e0 + Olds[1][q * 64 + d] * e1
                  + Olds[2][q * 64 + d] * e2 + Olds[3][q * 64 + d] * e3;
        out[(b * 2048 + q0 + q) * 64 + d] = val / L;
    }
}

extern "C" void kernel_launch(void* const* d_in, const int* in_sizes, int n_in,
                              void* d_out, int out_size, void* d_ws, size_t ws_size,
                              hipStream_t stream) {
    const float* Q   = (const float*)d_in[0];
    const float* K   = (const float*)d_in[1];
    const float* V   = (const float*)d_in[2];
    const int* mask  = (const int*)d_in[3];
    const float* Wq  = (const float*)d_in[4];
    const float* bq  = (const float*)d_in[5];
    const float* Wk  = (const float*)d_in[6];
    const float* bk  = (const float*)d_in[7];
    const float* Wv  = (const float*)d_in[8];
    const float* bv  = (const float*)d_in[9];
    float* out = (float*)d_out;

    char* ws = (char*)d_ws;
    unsigned short* Qb = (unsigned short*)(ws);                    // 1 MB
    unsigned short* Kb = (unsigned short*)(ws + (1u << 20));       // 1 MB
    unsigned short* Vt = (unsigned short*)(ws + (2u << 20));       // 1 MB
    unsigned short* Wb = (unsigned short*)(ws + (3u << 20));       // 384 KB

    hipLaunchKernelGGL(cvt_w_kernel, dim3(192), dim3(256), 0, stream, Wq, Wk, Wv, Wb);
    hipLaunchKernelGGL(proj_kernel, dim3(512, 3), dim3(64), 0, stream,
                       Q, K, V, Wb, bq, bk, bv, Qb, Kb, Vt);
    hipLaunchKernelGGL(attn_kernel, dim3(128, 4), dim3(256), 0, stream,
                       Qb, Kb, Vt, mask, out);
}